// Round 1
// baseline (1069.534 us; speedup 1.0000x reference)
//
#include <hip/hip_runtime.h>
#include <math.h>

// LLamaAttention decode: B=32 H=32 HKV=8 G=4 D=128 N=4096 BLOCK=16 NB=256
// Paged KV layout (from reference .reshape semantics): per physical block pb,
// element (kh, t, d) lives at Kcache[pb*16384 + kh*2048 + t*128 + d].
// Memory-bound: ~1.07 GB K+V gather per call -> ~170us floor @ 6.3 TB/s.

namespace {
constexpr int kBn    = 32;
constexpr int kH     = 32;
constexpr int kHKV   = 8;
constexpr int kG     = 4;     // H / HKV
constexpr int kD     = 128;
constexpr int kNB    = 256;   // blocks per sequence
constexpr int kBlockElems = 16 * kHKV * kD; // 16384 floats per physical block
constexpr int kHeadSlice  = 16 * kD;        // 2048 floats per (block, kv-head)
constexpr float kScale = 0.08838834764831845f;
constexpr int kWaves   = 16;
constexpr int kThreads = 1024;
}

__global__ __launch_bounds__(kThreads, 4) void attn_decode(
    const float* __restrict__ Q, const float* __restrict__ K,
    const float* __restrict__ V, const float* __restrict__ Kcache,
    const float* __restrict__ Vcache, const float* __restrict__ cosv,
    const float* __restrict__ sinv, const int* __restrict__ block_tables,
    float* __restrict__ out)
{
    __shared__ float qs[kG][kD];        // roped, pre-scaled Q for the 4 group heads
    __shared__ float kr[kD];            // roped current K
    __shared__ int   bt[kNB];
    __shared__ float mS[kWaves + 1][kG];
    __shared__ float lS[kWaves + 1][kG];
    __shared__ float accS[kWaves + 1][kG][kD];

    const int bkh = blockIdx.x;
    const int b   = bkh >> 3;
    const int kh  = bkh & 7;
    const int tid = threadIdx.x;

    // ---- Phase 0: stage RoPE'd Q/K, current V, block table into LDS ----
    if (tid < 512) {
        const int g = tid >> 7, d = tid & 127;
        const float c = cosv[b * kD + d], s = sinv[b * kD + d];
        const float* qp = Q + ((size_t)b * kH + g * kHKV + kh) * kD;
        const float x  = qp[d];
        const float xr = (d < 64) ? -qp[d + 64] : qp[d - 64];
        qs[g][d] = (x * c + xr * s) * kScale;
    } else if (tid < 640) {
        const int d = tid - 512;
        const float c = cosv[b * kD + d], s = sinv[b * kD + d];
        const float* kp = K + ((size_t)b * kHKV + kh) * kD;
        const float x  = kp[d];
        const float xr = (d < 64) ? -kp[d + 64] : kp[d - 64];
        kr[d] = x * c + xr * s;
    } else if (tid < 768) {
        const int d = tid - 640;
        const float v = V[((size_t)b * kHKV + kh) * kD + d];
        accS[kWaves][0][d] = v; accS[kWaves][1][d] = v;
        accS[kWaves][2][d] = v; accS[kWaves][3][d] = v;
    } else {
        const int i = tid - 768;   // 0..255
        bt[i] = block_tables[b * kNB + i];
    }
    __syncthreads();

    // ---- current-token score (virtual wave 16): wave 0 computes it ----
    if (tid < 64) {
        const int h = tid >> 4, li = tid & 15;
        float p = 0.f;
        #pragma unroll
        for (int j = 0; j < 8; ++j) p += qs[h][li * 8 + j] * kr[li * 8 + j];
        #pragma unroll
        for (int off = 1; off < 16; off <<= 1) p += __shfl_xor(p, off);
        if (li == 0) { mS[kWaves][h] = p; lS[kWaves][h] = 1.0f; }
    }

    // ---- Phase 1: flash-decode over cache blocks ----
    const int wave    = tid >> 6;
    const int lane    = tid & 63;
    const int quarter = lane >> 4;   // 16-lane group = one token
    const int li      = lane & 15;   // covers dims li*8 .. li*8+7

    float q[kG][8];
    #pragma unroll
    for (int h = 0; h < kG; ++h) {
        const float4 a = *(const float4*)&qs[h][li * 8];
        const float4 c = *(const float4*)&qs[h][li * 8 + 4];
        q[h][0] = a.x; q[h][1] = a.y; q[h][2] = a.z; q[h][3] = a.w;
        q[h][4] = c.x; q[h][5] = c.y; q[h][6] = c.z; q[h][7] = c.w;
    }

    float m[kG], l[kG], acc[kG][8];
    #pragma unroll
    for (int h = 0; h < kG; ++h) {
        m[h] = -INFINITY; l[h] = 0.f;
        #pragma unroll
        for (int j = 0; j < 8; ++j) acc[h][j] = 0.f;
    }

    for (int nb = wave; nb < kNB; nb += kWaves) {
        const int pb = bt[nb];
        const float* kb = Kcache + (size_t)pb * kBlockElems + (size_t)kh * kHeadSlice + li * 8;
        const float* vb = Vcache + (size_t)pb * kBlockElems + (size_t)kh * kHeadSlice + li * 8;

        float p[kG][4];
        #pragma unroll
        for (int t = 0; t < 4; ++t) {
            const int tok = t * 4 + quarter;
            const float4 k0 = *(const float4*)(kb + tok * kD);
            const float4 k1 = *(const float4*)(kb + tok * kD + 4);
            #pragma unroll
            for (int h = 0; h < kG; ++h) {
                p[h][t] = q[h][0] * k0.x + q[h][1] * k0.y + q[h][2] * k0.z + q[h][3] * k0.w
                        + q[h][4] * k1.x + q[h][5] * k1.y + q[h][6] * k1.z + q[h][7] * k1.w;
            }
        }
        // reduce each token's partial dot across its 16-lane group
        #pragma unroll
        for (int h = 0; h < kG; ++h) {
            #pragma unroll
            for (int t = 0; t < 4; ++t) {
                float s = p[h][t];
                s += __shfl_xor(s, 1); s += __shfl_xor(s, 2);
                s += __shfl_xor(s, 4); s += __shfl_xor(s, 8);
                p[h][t] = s;
            }
        }
        // last cache block: token 15 (= position 4095) is the current token, not cache
        if (nb == kNB - 1 && quarter == 3) {
            p[0][3] = -INFINITY; p[1][3] = -INFINITY;
            p[2][3] = -INFINITY; p[3][3] = -INFINITY;
        }
        // online softmax update (once per 16-token block)
        #pragma unroll
        for (int h = 0; h < kG; ++h) {
            float mb = fmaxf(fmaxf(p[h][0], p[h][1]), fmaxf(p[h][2], p[h][3]));
            mb = fmaxf(mb, __shfl_xor(mb, 16));
            mb = fmaxf(mb, __shfl_xor(mb, 32));
            const float mn = fmaxf(m[h], mb);
            const float alpha = __expf(m[h] - mn);
            m[h] = mn;
            float ps = 0.f;
            #pragma unroll
            for (int t = 0; t < 4; ++t) {
                const float e = __expf(p[h][t] - mn);
                p[h][t] = e; ps += e;
            }
            l[h] = l[h] * alpha + ps;
            #pragma unroll
            for (int j = 0; j < 8; ++j) acc[h][j] *= alpha;
        }
        // V accumulation
        #pragma unroll
        for (int t = 0; t < 4; ++t) {
            const int tok = t * 4 + quarter;
            const float4 v0 = *(const float4*)(vb + tok * kD);
            const float4 v1 = *(const float4*)(vb + tok * kD + 4);
            #pragma unroll
            for (int h = 0; h < kG; ++h) {
                const float e = p[h][t];
                acc[h][0] += e * v0.x; acc[h][1] += e * v0.y;
                acc[h][2] += e * v0.z; acc[h][3] += e * v0.w;
                acc[h][4] += e * v1.x; acc[h][5] += e * v1.y;
                acc[h][6] += e * v1.z; acc[h][7] += e * v1.w;
            }
        }
    }

    // ---- per-wave cross-quarter reduction, write partials to LDS ----
    #pragma unroll
    for (int h = 0; h < kG; ++h) {
        float lv = l[h];
        lv += __shfl_xor(lv, 16); lv += __shfl_xor(lv, 32);
        l[h] = lv;
        #pragma unroll
        for (int j = 0; j < 8; ++j) {
            float a = acc[h][j];
            a += __shfl_xor(a, 16); a += __shfl_xor(a, 32);
            acc[h][j] = a;
        }
    }
    if (lane < 16) {
        #pragma unroll
        for (int h = 0; h < kG; ++h)
            #pragma unroll
            for (int j = 0; j < 8; ++j) accS[wave][h][li * 8 + j] = acc[h][j];
    }
    if (lane == 0) {
        #pragma unroll
        for (int h = 0; h < kG; ++h) { mS[wave][h] = m[h]; lS[wave][h] = l[h]; }
    }
    __syncthreads();

    // ---- Phase 2: combine 16 wave-partials + current token, write out ----
    if (tid < 512) {
        const int g = tid >> 7, d = tid & 127;
        float mf = -INFINITY;
        #pragma unroll
        for (int w = 0; w <= kWaves; ++w) mf = fmaxf(mf, mS[w][g]);
        float lf = 0.f, af = 0.f;
        #pragma unroll
        for (int w = 0; w <= kWaves; ++w) {
            const float e = __expf(mS[w][g] - mf);
            lf += e * lS[w][g];
            af += e * accS[w][g][d];
        }
        out[((size_t)b * kH + g * kHKV + kh) * kD + d] = af / lf;
    }
}

extern "C" void kernel_launch(void* const* d_in, const int* in_sizes, int n_in,
                              void* d_out, int out_size, void* d_ws, size_t ws_size,
                              hipStream_t stream) {
    const float* Q   = (const float*)d_in[0];
    const float* K   = (const float*)d_in[1];
    const float* V   = (const float*)d_in[2];
    const float* Kc  = (const float*)d_in[3];
    const float* Vc  = (const float*)d_in[4];
    const float* cs  = (const float*)d_in[5];
    const float* sn  = (const float*)d_in[6];
    const int*   btb = (const int*)d_in[7];
    float* out = (float*)d_out;
    attn_decode<<<kBn * kHKV, kThreads, 0, stream>>>(Q, K, V, Kc, Vc, cs, sn, btb, out);
}

// Round 2
// 1032.256 us; speedup vs baseline: 1.0361x; 1.0361x over previous
//
#include <hip/hip_runtime.h>
#include <math.h>

// LLamaAttention decode: B=32 H=32 HKV=8 G=4 D=128 N=4096 BLOCK=16 NB=256
// Paged KV layout: element (pb, kh, t, d) at Kcache[pb*16384 + kh*2048 + t*128 + d].
// Memory-bound: ~1.07 GB K+V gather -> ~170us floor @ 6.3 TB/s.
// R2: hot loop has ZERO DS ops — 16-lane dot reduce via DPP row_ror on the
// VALU pipe; per-quarter independent online softmax (merge once at end);
// scores kept in log2 domain (log2e folded into Q scale) so v_exp_f32 is raw.

namespace {
constexpr int kBn    = 32;
constexpr int kH     = 32;
constexpr int kHKV   = 8;
constexpr int kG     = 4;     // H / HKV
constexpr int kD     = 128;
constexpr int kNB    = 256;   // blocks per sequence
constexpr int kBlockElems = 16 * kHKV * kD; // 16384 floats per physical block
constexpr int kHeadSlice  = 16 * kD;        // 2048 floats per (block, kv-head)
constexpr float kScale    = 0.08838834764831845f;
constexpr float kLog2e    = 1.4426950408889634f;
constexpr float kScaleL2  = kScale * kLog2e;   // scores in log2 domain
constexpr int kWaves   = 16;
constexpr int kThreads = 1024;
}

__device__ __forceinline__ float exp2_fast(float x) {
#if __has_builtin(__builtin_amdgcn_exp2f)
    return __builtin_amdgcn_exp2f(x);
#else
    return __expf(x * 0.6931471805599453f);
#endif
}

// x += rotate_within_16_lane_row(x, CTRL); 4 steps -> every lane of the row
// holds the full 16-lane sum. VALU pipe only (no DS).
template <int CTRL>
__device__ __forceinline__ float dpp_add(float x) {
    const int yi = __builtin_amdgcn_update_dpp(
        0, __float_as_int(x), CTRL, 0xf, 0xf, false);
    return x + __int_as_float(yi);
}
__device__ __forceinline__ float row_sum16(float x) {
    x = dpp_add<0x128>(x);  // row_ror:8
    x = dpp_add<0x124>(x);  // row_ror:4
    x = dpp_add<0x122>(x);  // row_ror:2
    x = dpp_add<0x121>(x);  // row_ror:1
    return x;
}

__global__ __launch_bounds__(kThreads, 4) void attn_decode(
    const float* __restrict__ Q, const float* __restrict__ K,
    const float* __restrict__ V, const float* __restrict__ Kcache,
    const float* __restrict__ Vcache, const float* __restrict__ cosv,
    const float* __restrict__ sinv, const int* __restrict__ block_tables,
    float* __restrict__ out)
{
    __shared__ float qs[kG][kD];        // roped Q * kScaleL2
    __shared__ float kr[kD];            // roped current K
    __shared__ int   bt[kNB];
    __shared__ float mS[kWaves + 1][kG];
    __shared__ float lS[kWaves + 1][kG];
    __shared__ float accS[kWaves + 1][kG][kD];

    const int bkh = blockIdx.x;
    const int b   = bkh >> 3;
    const int kh  = bkh & 7;
    const int tid = threadIdx.x;

    // ---- Phase 0: stage RoPE'd Q/K, current V, block table into LDS ----
    if (tid < 512) {
        const int g = tid >> 7, d = tid & 127;
        const float c = cosv[b * kD + d], s = sinv[b * kD + d];
        const float* qp = Q + ((size_t)b * kH + g * kHKV + kh) * kD;
        const float x  = qp[d];
        const float xr = (d < 64) ? -qp[d + 64] : qp[d - 64];
        qs[g][d] = (x * c + xr * s) * kScaleL2;
    } else if (tid < 640) {
        const int d = tid - 512;
        const float c = cosv[b * kD + d], s = sinv[b * kD + d];
        const float* kp = K + ((size_t)b * kHKV + kh) * kD;
        const float x  = kp[d];
        const float xr = (d < 64) ? -kp[d + 64] : kp[d - 64];
        kr[d] = x * c + xr * s;
    } else if (tid < 768) {
        const int d = tid - 640;
        const float v = V[((size_t)b * kHKV + kh) * kD + d];
        accS[kWaves][0][d] = v; accS[kWaves][1][d] = v;
        accS[kWaves][2][d] = v; accS[kWaves][3][d] = v;
    } else {
        const int i = tid - 768;   // 0..255
        bt[i] = block_tables[b * kNB + i];
    }
    __syncthreads();

    // ---- current-token score (virtual partial 16), log2 domain ----
    if (tid < 64) {
        const int h = tid >> 4, li = tid & 15;
        float p = 0.f;
        #pragma unroll
        for (int j = 0; j < 8; ++j) p += qs[h][li * 8 + j] * kr[li * 8 + j];
        #pragma unroll
        for (int off = 1; off < 16; off <<= 1) p += __shfl_xor(p, off);
        if (li == 0) { mS[kWaves][h] = p; lS[kWaves][h] = 1.0f; }
    }

    // ---- Phase 1: flash-decode over cache blocks ----
    const int wave    = tid >> 6;
    const int lane    = tid & 63;
    const int quarter = lane >> 4;   // 16-lane DPP row = one token
    const int li      = lane & 15;   // covers dims li*8 .. li*8+7

    float q[kG][8];
    #pragma unroll
    for (int h = 0; h < kG; ++h) {
        const float4 a = *(const float4*)&qs[h][li * 8];
        const float4 c = *(const float4*)&qs[h][li * 8 + 4];
        q[h][0] = a.x; q[h][1] = a.y; q[h][2] = a.z; q[h][3] = a.w;
        q[h][4] = c.x; q[h][5] = c.y; q[h][6] = c.z; q[h][7] = c.w;
    }

    float m[kG], l[kG], acc[kG][8];
    #pragma unroll
    for (int h = 0; h < kG; ++h) {
        m[h] = -INFINITY; l[h] = 0.f;
        #pragma unroll
        for (int j = 0; j < 8; ++j) acc[h][j] = 0.f;
    }

    for (int nb = wave; nb < kNB; nb += kWaves) {
        const int pb = bt[nb];
        const float* kb = Kcache + (size_t)pb * kBlockElems + (size_t)kh * kHeadSlice + li * 8;
        const float* vb = Vcache + (size_t)pb * kBlockElems + (size_t)kh * kHeadSlice + li * 8;

        float p[kG][4];
        #pragma unroll
        for (int t = 0; t < 4; ++t) {
            const int tok = t * 4 + quarter;
            const float4 k0 = *(const float4*)(kb + tok * kD);
            const float4 k1 = *(const float4*)(kb + tok * kD + 4);
            #pragma unroll
            for (int h = 0; h < kG; ++h) {
                p[h][t] = q[h][0] * k0.x + q[h][1] * k0.y + q[h][2] * k0.z + q[h][3] * k0.w
                        + q[h][4] * k1.x + q[h][5] * k1.y + q[h][6] * k1.z + q[h][7] * k1.w;
            }
        }
        // reduce each token's partial dot across its 16-lane row (VALU DPP)
        #pragma unroll
        for (int h = 0; h < kG; ++h) {
            #pragma unroll
            for (int t = 0; t < 4; ++t) p[h][t] = row_sum16(p[h][t]);
        }
        // last cache block: token 15 (= position 4095) is current token, not cache
        if (nb == kNB - 1 && quarter == 3) {
            p[0][3] = -INFINITY; p[1][3] = -INFINITY;
            p[2][3] = -INFINITY; p[3][3] = -INFINITY;
        }
        // per-quarter online softmax (no cross-lane ops; log2 domain)
        #pragma unroll
        for (int h = 0; h < kG; ++h) {
            const float mb = fmaxf(fmaxf(p[h][0], p[h][1]), fmaxf(p[h][2], p[h][3]));
            const float mn = fmaxf(m[h], mb);
            const float alpha = exp2_fast(m[h] - mn);
            m[h] = mn;
            float ps = 0.f;
            #pragma unroll
            for (int t = 0; t < 4; ++t) {
                const float e = exp2_fast(p[h][t] - mn);
                p[h][t] = e; ps += e;
            }
            l[h] = l[h] * alpha + ps;
            #pragma unroll
            for (int j = 0; j < 8; ++j) acc[h][j] *= alpha;
        }
        // V accumulation
        #pragma unroll
        for (int t = 0; t < 4; ++t) {
            const int tok = t * 4 + quarter;
            const float4 v0 = *(const float4*)(vb + tok * kD);
            const float4 v1 = *(const float4*)(vb + tok * kD + 4);
            #pragma unroll
            for (int h = 0; h < kG; ++h) {
                const float e = p[h][t];
                acc[h][0] += e * v0.x; acc[h][1] += e * v0.y;
                acc[h][2] += e * v0.z; acc[h][3] += e * v0.w;
                acc[h][4] += e * v1.x; acc[h][5] += e * v1.y;
                acc[h][6] += e * v1.z; acc[h][7] += e * v1.w;
            }
        }
    }

    // ---- merge the 4 independent quarter-softmaxes within the wave ----
    #pragma unroll
    for (int h = 0; h < kG; ++h) {
        float mw = m[h];
        mw = fmaxf(mw, __shfl_xor(mw, 16));
        mw = fmaxf(mw, __shfl_xor(mw, 32));
        const float al = exp2_fast(m[h] - mw);
        m[h] = mw;
        float lv = l[h] * al;
        lv += __shfl_xor(lv, 16); lv += __shfl_xor(lv, 32);
        l[h] = lv;
        #pragma unroll
        for (int j = 0; j < 8; ++j) {
            float a = acc[h][j] * al;
            a += __shfl_xor(a, 16); a += __shfl_xor(a, 32);
            acc[h][j] = a;
        }
    }
    if (lane < 16) {
        #pragma unroll
        for (int h = 0; h < kG; ++h)
            #pragma unroll
            for (int j = 0; j < 8; ++j) accS[wave][h][li * 8 + j] = acc[h][j];
    }
    if (lane == 0) {
        #pragma unroll
        for (int h = 0; h < kG; ++h) { mS[wave][h] = m[h]; lS[wave][h] = l[h]; }
    }
    __syncthreads();

    // ---- Phase 2: combine 16 wave-partials + current token, write out ----
    if (tid < 512) {
        const int g = tid >> 7, d = tid & 127;
        float mf = -INFINITY;
        #pragma unroll
        for (int w = 0; w <= kWaves; ++w) mf = fmaxf(mf, mS[w][g]);
        float lf = 0.f, af = 0.f;
        #pragma unroll
        for (int w = 0; w <= kWaves; ++w) {
            const float e = exp2_fast(mS[w][g] - mf);
            lf += e * lS[w][g];
            af += e * accS[w][g][d];
        }
        out[((size_t)b * kH + g * kHKV + kh) * kD + d] = af / lf;
    }
}

extern "C" void kernel_launch(void* const* d_in, const int* in_sizes, int n_in,
                              void* d_out, int out_size, void* d_ws, size_t ws_size,
                              hipStream_t stream) {
    const float* Q   = (const float*)d_in[0];
    const float* K   = (const float*)d_in[1];
    const float* V   = (const float*)d_in[2];
    const float* Kc  = (const float*)d_in[3];
    const float* Vc  = (const float*)d_in[4];
    const float* cs  = (const float*)d_in[5];
    const float* sn  = (const float*)d_in[6];
    const int*   btb = (const int*)d_in[7];
    float* out = (float*)d_out;
    attn_decode<<<kBn * kHKV, kThreads, 0, stream>>>(Q, K, V, Kc, Vc, cs, sn, btb, out);
}